// Round 7
// baseline (548.104 us; speedup 1.0000x reference)
//
#include <hip/hip_runtime.h>

// Problem constants (B,T,D,H,KVH fixed by the reference)
#define NB 2
#define NT 2048
#define ND 2048
#define NH 16
#define NKVH 4
#define NHD 128
#define NHALF 64
#define NREP (NH / NKVH)
#define MFIX 12.0f  // fixed softmax max: |score| <= sqrt(128) ~= 11.32 after zc-rmsnorm

typedef __bf16 bf16x8 __attribute__((ext_vector_type(8)));
typedef unsigned short u16x8 __attribute__((ext_vector_type(8)));
typedef unsigned short u16x4 __attribute__((ext_vector_type(4)));
typedef float f32x4 __attribute__((ext_vector_type(4)));

__device__ __forceinline__ unsigned short f2b(float f) {
  union { float f; unsigned int u; } v; v.f = f;
  unsigned int r = v.u + 0x7FFFu + ((v.u >> 16) & 1u);
  return (unsigned short)(r >> 16);
}

// async global->LDS DMA, 16B per lane. LDS dest = wave-uniform base + lane*16.
__device__ __forceinline__ void glds16(const unsigned short* g, unsigned short* l) {
  __builtin_amdgcn_global_load_lds(
      (__attribute__((address_space(1))) unsigned int*)(unsigned long long)g,
      (__attribute__((address_space(3))) unsigned int*)(unsigned int)(unsigned long long)l,
      16, 0, 0);
}

// ---------- fused prep: f2bf(q) | f2bf(kv) | wtrans x4, one dispatch ----------
__device__ __forceinline__ void f2bf_body(const float* __restrict__ in,
                                          unsigned short* __restrict__ out, int lb) {
  const size_t i = (size_t)(lb * 256 + threadIdx.x) * 8;
  float4 a = *(const float4*)(in + i);
  float4 b = *(const float4*)(in + i + 4);
  u16x8 r;
  r[0] = f2b(a.x); r[1] = f2b(a.y); r[2] = f2b(a.z); r[3] = f2b(a.w);
  r[4] = f2b(b.x); r[5] = f2b(b.y); r[6] = f2b(b.z); r[7] = f2b(b.w);
  *(u16x8*)(out + i) = r;
}

__device__ __forceinline__ void wtrans_body(const float* __restrict__ in,
                                            unsigned short* __restrict__ out,
                                            int K, int N, int bx, int by,
                                            float (*tile)[33]) {
  const int k0 = by * 32, n0 = bx * 32;
  const int x = threadIdx.x & 31, y8 = threadIdx.x >> 5;
#pragma unroll
  for (int j = 0; j < 4; ++j) {
    const int y = y8 + j * 8;
    tile[y][x] = in[(size_t)(k0 + y) * N + n0 + x];
  }
  __syncthreads();
#pragma unroll
  for (int j = 0; j < 4; ++j) {
    const int y = y8 + j * 8;
    out[(size_t)(n0 + y) * K + k0 + x] = f2b(tile[x][y]);
  }
}

__global__ __launch_bounds__(256) void prep_all(const float* __restrict__ q_input,
                                                unsigned short* __restrict__ Qb16,
                                                const float* __restrict__ kv_input,
                                                unsigned short* __restrict__ KVb16,
                                                const float* __restrict__ Wq,
                                                unsigned short* __restrict__ Wqt,
                                                const float* __restrict__ Wk,
                                                const float* __restrict__ Wv,
                                                unsigned short* __restrict__ WkvT,
                                                const float* __restrict__ Wo,
                                                unsigned short* __restrict__ Wot) {
  __shared__ float tile[32][33];
  const int l = blockIdx.x;
  if (l < 4096) {
    f2bf_body(q_input, Qb16, l);
  } else if (l < 8192) {
    f2bf_body(kv_input, KVb16, l - 4096);
  } else if (l < 12288) {
    const int l2 = l - 8192;
    wtrans_body(Wq, Wqt, 2048, 2048, l2 & 63, l2 >> 6, tile);
  } else if (l < 13312) {
    const int l2 = l - 12288;
    wtrans_body(Wk, WkvT, 2048, 512, l2 & 15, l2 >> 4, tile);
  } else if (l < 14336) {
    const int l2 = l - 13312;
    wtrans_body(Wv, WkvT + (size_t)512 * 2048, 2048, 512, l2 & 15, l2 >> 4, tile);
  } else {
    const int l2 = l - 14336;
    wtrans_body(Wo, Wot, 2048, 2048, l2 & 63, l2 >> 6, tile);
  }
}

// ---------- GEMM compute core: acc = A(M,K)bf16 @ Bt(N,K)bf16^T tile (m0,n0) ----------
// 128x128 tile, BK=64, 2-phase double-buffered global_load_lds pipeline.
// Linear LDS [128][64]; conflict-free via XOR-granule swizzle on BOTH sides.
__device__ __forceinline__ void gemm_mm(const unsigned short* __restrict__ A,
                                        const unsigned short* __restrict__ Bt,
                                        int K, int m0, int n0,
                                        unsigned short* As, unsigned short* Bs,
                                        f32x4 (&acc)[4][4]) {
  const int tid = threadIdx.x;
  const int wave = tid >> 6, lane = tid & 63;
  const int wm = wave >> 1, wn = wave & 1;
  const int quad = lane >> 4, c = lane & 15;
  const int lr = lane >> 3;                 // 0..7: row within an 8-row stage group
  const int gsw = ((lane & 7) ^ lr) * 8;    // pre-swizzled source granule (shorts)

  const unsigned short* pa[4];
  const unsigned short* pb[4];
  unsigned short* da[4];
  unsigned short* db[4];
#pragma unroll
  for (int j = 0; j < 4; ++j) {
    const int rb = j * 32 + wave * 8;       // 8-row group base (multiple of 8)
    pa[j] = A + (size_t)(m0 + rb + lr) * K + gsw;
    pb[j] = Bt + (size_t)(n0 + rb + lr) * K + gsw;
    da[j] = As + rb * 64;
    db[j] = Bs + rb * 64;
  }

  const f32x4 zero = {0.f, 0.f, 0.f, 0.f};
#pragma unroll
  for (int sm = 0; sm < 4; ++sm)
#pragma unroll
    for (int sn = 0; sn < 4; ++sn) acc[sm][sn] = zero;

  const int nsteps = K >> 6;
  int cur = 0;

  // prologue: stage K-step 0 into buffer 0
#pragma unroll
  for (int j = 0; j < 4; ++j) { glds16(pa[j], da[j]); glds16(pb[j], db[j]); }
  __syncthreads();

  for (int t = 0; t < nsteps; ++t) {
    const int nxt = (cur ^ 1) * (128 * 64);
    if (t + 1 < nsteps) {  // issue next K-step's DMA; latency hides under MFMA
      const int kn = (t + 1) << 6;
#pragma unroll
      for (int j = 0; j < 4; ++j) {
        glds16(pa[j] + kn, da[j] + nxt);
        glds16(pb[j] + kn, db[j] + nxt);
      }
    }
    const unsigned short* Ab = As + cur * (128 * 64);
    const unsigned short* Bb = Bs + cur * (128 * 64);
#pragma unroll
    for (int kk = 0; kk < 2; ++kk) {
      const int g = ((kk * 4 + quad) ^ (c & 7)) * 8;  // swizzled read granule
      bf16x8 af[4];
#pragma unroll
      for (int sm = 0; sm < 4; ++sm)
        af[sm] = *(const bf16x8*)&Ab[(wm * 64 + sm * 16 + c) * 64 + g];
#pragma unroll
      for (int sn = 0; sn < 4; ++sn) {
        bf16x8 bfr = *(const bf16x8*)&Bb[(wn * 64 + sn * 16 + c) * 64 + g];
#pragma unroll
        for (int sm = 0; sm < 4; ++sm)
          acc[sm][sn] = __builtin_amdgcn_mfma_f32_16x16x32_bf16(af[sm], bfr, acc[sm][sn], 0, 0, 0);
      }
    }
    // drain own glds (vmcnt) + join: next buffer globally ready.
    __syncthreads();
    cur ^= 1;
  }
  // note: loop ends with __syncthreads -> LDS reusable by epilogues
}

// ---------- standalone GEMM (O-projection) ----------
__global__ __launch_bounds__(256) void gemm128(const unsigned short* __restrict__ A,
                                               const unsigned short* __restrict__ Bt,
                                               float* __restrict__ C,
                                               int M, int N, int K) {
  __shared__ __align__(16) unsigned char smem[65536];
  unsigned short* As = (unsigned short*)smem;
  unsigned short* Bs = (unsigned short*)(smem + 32768);
  const int gx = gridDim.x;
  const int nwg = gx * gridDim.y;
  int lin = blockIdx.y * gx + blockIdx.x;
  lin = (lin & 7) * (nwg >> 3) + (lin >> 3);  // T1 XCD swizzle (nwg%8==0)
  const int m0 = (lin / gx) * 128, n0 = (lin % gx) * 128;
  f32x4 acc[4][4];
  gemm_mm(A, Bt, K, m0, n0, As, Bs, acc);
  const int tid = threadIdx.x;
  const int wave = tid >> 6, lane = tid & 63;
  const int wm = wave >> 1, wn = wave & 1;
  const int quad = lane >> 4, c = lane & 15;
#pragma unroll
  for (int sm = 0; sm < 4; ++sm)
#pragma unroll
    for (int sn = 0; sn < 4; ++sn) {
      const int row = m0 + wm * 64 + sm * 16 + quad * 4;
      const int col = n0 + wn * 64 + sn * 16 + c;
#pragma unroll
      for (int r = 0; r < 4; ++r)
        C[(size_t)(row + r) * N + col] = acc[sm][sn][r];
    }
}

// ---------- epilogue: zc-rmsnorm + rope + bf16, straight from accumulators ----------
__device__ __forceinline__ void epi_normrope(f32x4 (&acc)[4][4], float* xb,
                                             unsigned short* __restrict__ dst,
                                             const float* __restrict__ scale,
                                             const float* __restrict__ cosp,
                                             const float* __restrict__ sinp,
                                             int t0, float outscale) {
  const int tid = threadIdx.x;
  const int wave = tid >> 6, lane = tid & 63;
  const int wm = wave >> 1, wn = wave & 1;
  const int quad = lane >> 4, c = lane & 15;
#pragma unroll
  for (int sm = 0; sm < 4; ++sm)
#pragma unroll
    for (int sn = 0; sn < 4; ++sn) {
      const int row = wm * 64 + sm * 16 + quad * 4;
      const int col = wn * 64 + sn * 16 + c;
#pragma unroll
      for (int r = 0; r < 4; ++r)
        xb[(row + r) * 128 + col] = acc[sm][sn][r];
    }
  __syncthreads();
#pragma unroll
  for (int sm = 0; sm < 4; ++sm) {
#pragma unroll
    for (int r = 0; r < 4; ++r) {
      const int row = wm * 64 + sm * 16 + quad * 4 + r;
      float par[4];
      float ps = 0.f;
#pragma unroll
      for (int sn = 0; sn < 4; ++sn) {
        const float own = acc[sm][sn][r];
        par[sn] = xb[row * 128 + ((wn ^ 1) * 64 + sn * 16 + c)];
        ps += own * own + par[sn] * par[sn];
      }
      ps += __shfl_xor(ps, 1, 64);
      ps += __shfl_xor(ps, 2, 64);
      ps += __shfl_xor(ps, 4, 64);
      ps += __shfl_xor(ps, 8, 64);
      const float inv = 1.0f / sqrtf(ps * (1.0f / NHD) + 1e-6f);
      const int t = t0 + row;
#pragma unroll
      for (int sn = 0; sn < 4; ++sn) {
        const int d = wn * 64 + sn * 16 + c;
        const int dd = sn * 16 + c;  // rope index (d & 63)
        const float n_own = (1.0f + scale[d]) * acc[sm][sn][r] * inv;
        const float n_par = (1.0f + scale[d ^ 64]) * par[sn] * inv;
        const float cc = cosp[t * NHALF + dd], ss = sinp[t * NHALF + dd];
        const float o = (wn == 0) ? (n_own * cc - n_par * ss)
                                  : (n_own * cc + n_par * ss);
        dst[(size_t)row * NHD + d] = f2b(o * outscale);
      }
    }
  }
}

// ---------- epilogue: V transpose via LDS -> Vtg[d][t] bf16, coalesced out ----------
__device__ __forceinline__ void epi_vtrans(f32x4 (&acc)[4][4],
                                           unsigned short* vb,  // [128][136]
                                           unsigned short* __restrict__ dst) {
  const int tid = threadIdx.x;
  const int wave = tid >> 6, lane = tid & 63;
  const int wm = wave >> 1, wn = wave & 1;
  const int quad = lane >> 4, c = lane & 15;
#pragma unroll
  for (int sm = 0; sm < 4; ++sm)
#pragma unroll
    for (int sn = 0; sn < 4; ++sn) {
      const int row = wm * 64 + sm * 16 + quad * 4;
      const int col = wn * 64 + sn * 16 + c;
      u16x4 pk;
      pk[0] = f2b(acc[sm][sn][0]); pk[1] = f2b(acc[sm][sn][1]);
      pk[2] = f2b(acc[sm][sn][2]); pk[3] = f2b(acc[sm][sn][3]);
      *(u16x4*)&vb[col * 136 + row] = pk;
    }
  __syncthreads();
#pragma unroll
  for (int i = 0; i < 32; ++i) {
    const int d = wave * 32 + i;
    const unsigned int v = *(const unsigned int*)&vb[d * 136 + lane * 2];
    *(unsigned int*)&dst[(size_t)d * NT + lane * 2] = v;
  }
}

// ---------- fused Q-proj + KV-proj + norm/rope/vtrans epilogues (768 blocks) ----------
__global__ __launch_bounds__(256) void gemm_qkv(const unsigned short* __restrict__ Aq,
                                                const unsigned short* __restrict__ Wqt,
                                                const unsigned short* __restrict__ Akv,
                                                const unsigned short* __restrict__ Wkv,
                                                unsigned short* __restrict__ Qh,
                                                unsigned short* __restrict__ Kh,
                                                unsigned short* __restrict__ Vtg,
                                                const float* __restrict__ q_scale,
                                                const float* __restrict__ k_scale,
                                                const float* __restrict__ cosp,
                                                const float* __restrict__ sinp) {
  __shared__ __align__(16) unsigned char smem[65536];
  unsigned short* As = (unsigned short*)smem;
  unsigned short* Bs = (unsigned short*)(smem + 32768);
  int lin = blockIdx.x;
  lin = (lin & 7) * 96 + (lin >> 3);  // XCD swizzle, nwg = 768
  f32x4 acc[4][4];
  if (lin < 512) {
    const int m0 = (lin >> 4) * 128, n0 = (lin & 15) * 128;
    gemm_mm(Aq, Wqt, 2048, m0, n0, As, Bs, acc);
    const int b = m0 >> 11, t0 = m0 & 2047, h = n0 >> 7;
    epi_normrope(acc, (float*)smem,
                 Qh + ((size_t)(b * NH + h) * NT + t0) * NHD,
                 q_scale, cosp, sinp, t0, 0.08838834764831845f);
  } else {
    const int l2 = lin - 512;
    const int m0 = (l2 >> 3) * 128, n0 = (l2 & 7) * 128;
    gemm_mm(Akv, Wkv, 2048, m0, n0, As, Bs, acc);
    const int b = m0 >> 11, t0 = m0 & 2047;
    if (n0 < 512) {
      const int g = n0 >> 7;
      epi_normrope(acc, (float*)smem,
                   Kh + ((size_t)(b * NKVH + g) * NT + t0) * NHD,
                   k_scale, cosp, sinp, t0, 1.0f);
    } else {
      const int g = (n0 - 512) >> 7;
      epi_vtrans(acc, (unsigned short*)smem,
                 Vtg + ((size_t)(b * NKVH + g) * NHD) * NT + t0);
    }
  }
}

// ---------- MFMA causal flash attention, 64-row Q-tiles ----------
// grid (B*H, 32). Block = 64 q-rows (4 waves x 16 rows), K-tiles of 64 keys.
// Fixed-max softmax (MFIX); T14 reg prefetch. NO setprio (r6: -13% in this
// 4-wave lockstep structure — m190 regime, not m191).
// Double-buffered K/V LDS -> ONE barrier per K-tile: a wave writing buf[kt&1]
// at tile kt+2 has passed barrier(kt+1); every wave passing that barrier has
// drained (lgkmcnt) its reads of buf[kt&1] (they precede its write(kt+1) in
// program order). LDS 77312 B -> 2 blocks/CU; grid 1024 = exactly 2x512.
__global__ __launch_bounds__(256, 2) void attn64(const unsigned short* __restrict__ Qh,
                                                 const unsigned short* __restrict__ Kh,
                                                 const unsigned short* __restrict__ Vtg,
                                                 unsigned short* __restrict__ O) {
  __shared__ unsigned short Kt[2][64 * 132];  // [buf][key][d]
  __shared__ unsigned short Vt[2][128 * 68];  // [buf][d][key]
  __shared__ unsigned short Pt[64 * 68];      // [qrow][key], wave-private 16-row slabs
  const int bh = blockIdx.x;
  const int b = bh / NH, h = bh % NH, g = h / NREP;
  const int y = blockIdx.y;
  const int a = y & 7, bb = y >> 3;
  // CU-balanced qt map: each a-group gets {a, a+8, 31-a, 23-a} (sum = 62, constant)
  const int qt = (bb == 0) ? a : (bb == 1) ? a + 8 : (bb == 2) ? 31 - a : 23 - a;
  const int tid = threadIdx.x;
  const int w = tid >> 6, lane = tid & 63;
  const int quad = lane >> 4, c = lane & 15;

  // Q A-fragments: rows qt*64 + w*16 + c, k = ch*32 + quad*8 + j
  bf16x8 qf[4];
  {
    const unsigned short* qp =
        Qh + ((size_t)(b * NH + h) * NT + qt * 64 + w * 16 + c) * NHD + quad * 8;
#pragma unroll
    for (int ch = 0; ch < 4; ++ch) qf[ch] = *(const bf16x8*)(qp + ch * 32);
  }

  f32x4 acc_o[8] = {};              // [n2]: row quad*4+r, dim n2*16+c
  float lsum[4] = {0.f, 0.f, 0.f, 0.f};
  const size_t kbase = (size_t)(b * NKVH + g) * NT * NHD;
  const size_t vbase = (size_t)(b * NKVH + g) * NHD * NT;
  const int nkt = qt + 1;

  // prologue: K/V tile 0 -> regs
  u16x8 kreg[4], vreg[4];
#pragma unroll
  for (int j = 0; j < 4; ++j) {
    const int f = j * 256 + tid;
    kreg[j] = *(const u16x8*)&Kh[kbase + (size_t)(f >> 4) * NHD + (f & 15) * 8];
    vreg[j] = *(const u16x8*)&Vtg[vbase + (size_t)(f >> 3) * NT + (f & 7) * 8];
  }

  for (int kt = 0; kt < nkt; ++kt) {
    unsigned short* Kb = Kt[kt & 1];
    unsigned short* Vb = Vt[kt & 1];
    // write staged tile to LDS buffer kt&1
#pragma unroll
    for (int j = 0; j < 4; ++j) {
      const int f = j * 256 + tid;
      *(u16x8*)&Kb[(f >> 4) * 132 + (f & 15) * 8] = kreg[j];
      *(u16x8*)&Vb[(f >> 3) * 68 + (f & 7) * 8] = vreg[j];
    }
    __syncthreads();  // single barrier per tile (see header comment)

    // prefetch next tile into regs (vmcnt drains at next iter's LDS write)
    if (kt + 1 < nkt) {
      const int k0 = (kt + 1) * 64;
#pragma unroll
      for (int j = 0; j < 4; ++j) {
        const int f = j * 256 + tid;
        kreg[j] = *(const u16x8*)&Kh[kbase + (size_t)(k0 + (f >> 4)) * NHD + (f & 15) * 8];
        vreg[j] = *(const u16x8*)&Vtg[vbase + (size_t)(f >> 3) * NT + k0 + (f & 7) * 8];
      }
    }

    // ---- S = Q K^T (16 x 64) ----
    f32x4 s[4] = {};
#pragma unroll
    for (int n = 0; n < 4; ++n)
#pragma unroll
      for (int ch = 0; ch < 4; ++ch) {
        bf16x8 kf = *(const bf16x8*)&Kb[(n * 16 + c) * 132 + ch * 32 + quad * 8];
        s[n] = __builtin_amdgcn_mfma_f32_16x16x32_bf16(qf[ch], kf, s[n], 0, 0, 0);
      }

    // ---- fixed-max softmax; P -> LDS (bf16) ----
    const bool dmask = (kt == qt);  // only the diagonal tile masks
#pragma unroll
    for (int r = 0; r < 4; ++r) {
      float v0 = s[0][r], v1 = s[1][r], v2 = s[2][r], v3 = s[3][r];
      const int lrow = w * 16 + quad * 4 + r;  // row within block; key offset n*16+c
      if (dmask) {
        if (c > lrow) v0 = -1e30f;
        if (16 + c > lrow) v1 = -1e30f;
        if (32 + c > lrow) v2 = -1e30f;
        if (48 + c > lrow) v3 = -1e30f;
      }
      const float p0 = __expf(v0 - MFIX), p1 = __expf(v1 - MFIX);
      const float p2 = __expf(v2 - MFIX), p3 = __expf(v3 - MFIX);
      lsum[r] += (p0 + p1) + (p2 + p3);
      Pt[lrow * 68 + c] = f2b(p0);
      Pt[lrow * 68 + 16 + c] = f2b(p1);
      Pt[lrow * 68 + 32 + c] = f2b(p2);
      Pt[lrow * 68 + 48 + c] = f2b(p3);
    }

    // ---- O += P V ----
#pragma unroll
    for (int kc2 = 0; kc2 < 2; ++kc2) {
      bf16x8 pf = *(const bf16x8*)&Pt[(w * 16 + c) * 68 + kc2 * 32 + quad * 8];
#pragma unroll
      for (int n2 = 0; n2 < 8; ++n2) {
        bf16x8 vf = *(const bf16x8*)&Vb[(n2 * 16 + c) * 68 + kc2 * 32 + quad * 8];
        acc_o[n2] = __builtin_amdgcn_mfma_f32_16x16x32_bf16(pf, vf, acc_o[n2], 0, 0, 0);
      }
    }
    // no end-of-tile barrier: double buffer + in-order per-wave DS ops
  }

  // one cross-lane l reduction (within 16-lane c-group)
#pragma unroll
  for (int r = 0; r < 4; ++r) {
    float l = lsum[r];
    l += __shfl_xor(l, 1, 64);
    l += __shfl_xor(l, 2, 64);
    l += __shfl_xor(l, 4, 64);
    l += __shfl_xor(l, 8, 64);
    lsum[r] = l;
  }

#pragma unroll
  for (int r = 0; r < 4; ++r) {
    const float invl = 1.0f / lsum[r];
    const int qrow = qt * 64 + w * 16 + quad * 4 + r;
    unsigned short* op = O + ((size_t)(b * NT + qrow) * NH + h) * NHD + c;
#pragma unroll
    for (int n2 = 0; n2 < 8; ++n2) op[n2 * 16] = f2b(acc_o[n2][r] * invl);
  }
}

extern "C" void kernel_launch(void* const* d_in, const int* in_sizes, int n_in,
                              void* d_out, int out_size, void* d_ws, size_t ws_size,
                              hipStream_t stream) {
  (void)in_sizes; (void)n_in; (void)out_size; (void)ws_size;
  const float* q_input  = (const float*)d_in[0];
  const float* kv_input = (const float*)d_in[1];
  // d_in[2] = mask (static causal tril) — applied analytically
  const float* cosp = (const float*)d_in[3];
  const float* sinp = (const float*)d_in[4];
  const float* Wq = (const float*)d_in[5];
  const float* Wk = (const float*)d_in[6];
  const float* Wv = (const float*)d_in[7];
  const float* q_scale = (const float*)d_in[8];
  const float* k_scale = (const float*)d_in[9];
  const float* Wo = (const float*)d_in[10];
  float* out = (float*)d_out;

  // workspace carve (~80 MB)
  char* p = (char*)d_ws;
  unsigned short* Qb16  = (unsigned short*)p; p += (size_t)NB * NT * ND * 2;  // 16.8 MB
  unsigned short* KVb16 = (unsigned short*)p; p += (size_t)NB * NT * ND * 2;  // 16.8 MB
  unsigned short* Qh  = (unsigned short*)p; p += (size_t)NB * NH * NT * NHD * 2;    // 16.8 MB
  unsigned short* Kh  = (unsigned short*)p; p += (size_t)NB * NKVH * NT * NHD * 2;  // 4.2 MB
  unsigned short* Vtg = (unsigned short*)p; p += (size_t)NB * NKVH * NT * NHD * 2;  // 4.2 MB
  unsigned short* Wqt  = (unsigned short*)p; p += (size_t)ND * ND * 2;         // 8.4 MB
  unsigned short* WkvT = (unsigned short*)p; p += (size_t)1024 * ND * 2;       // 4.2 MB
  unsigned short* Wot  = (unsigned short*)p; p += (size_t)ND * ND * 2;         // 8.4 MB
  // alias: Qb16 dead after gemm_qkv -> reuse as attention output Ob
  unsigned short* Ob = Qb16;

  const dim3 blk(256);
  const int M = NB * NT;  // 4096

  // 1) all prep (activation cvt + weight transposes) in one dispatch
  prep_all<<<dim3(18432), blk, 0, stream>>>(q_input, Qb16, kv_input, KVb16,
                                            Wq, Wqt, Wk, Wv, WkvT, Wo, Wot);

  // 2) Q-proj + KV-proj + norm/rope/vtrans epilogues, one dispatch (768 blocks)
  gemm_qkv<<<dim3(768), blk, 0, stream>>>(Qb16, Wqt, KVb16, WkvT,
                                          Qh, Kh, Vtg, q_scale, k_scale, cosp, sinp);

  // 3) MFMA causal GQA flash attention -> Ob (B,T,H,HD)
  attn64<<<dim3(NB * NH, 32), blk, 0, stream>>>(Qh, Kh, Vtg, Ob);

  // 4) output projection -> d_out (f32)
  gemm128<<<dim3(ND / 128, M / 128), blk, 0, stream>>>(Ob, Wot, out, M, ND, ND);
}

// Round 8
// 344.968 us; speedup vs baseline: 1.5889x; 1.5889x over previous
//
#include <hip/hip_runtime.h>

// Problem constants (B,T,D,H,KVH fixed by the reference)
#define NB 2
#define NT 2048
#define ND 2048
#define NH 16
#define NKVH 4
#define NHD 128
#define NHALF 64
#define NREP (NH / NKVH)
#define MFIX 12.0f  // fixed softmax max: |score| <= sqrt(128) ~= 11.32 after zc-rmsnorm

typedef __bf16 bf16x8 __attribute__((ext_vector_type(8)));
typedef unsigned short u16x8 __attribute__((ext_vector_type(8)));
typedef unsigned short u16x4 __attribute__((ext_vector_type(4)));
typedef float f32x4 __attribute__((ext_vector_type(4)));

__device__ __forceinline__ unsigned short f2b(float f) {
  union { float f; unsigned int u; } v; v.f = f;
  unsigned int r = v.u + 0x7FFFu + ((v.u >> 16) & 1u);
  return (unsigned short)(r >> 16);
}

// async global->LDS DMA, 16B per lane. LDS dest = wave-uniform base + lane*16.
__device__ __forceinline__ void glds16(const unsigned short* g, unsigned short* l) {
  __builtin_amdgcn_global_load_lds(
      (__attribute__((address_space(1))) unsigned int*)(unsigned long long)g,
      (__attribute__((address_space(3))) unsigned int*)(unsigned int)(unsigned long long)l,
      16, 0, 0);
}

// ---------- fused prep: f2bf(q) | f2bf(kv) | wtrans x4, one dispatch ----------
__device__ __forceinline__ void f2bf_body(const float* __restrict__ in,
                                          unsigned short* __restrict__ out, int lb) {
  const size_t i = (size_t)(lb * 256 + threadIdx.x) * 8;
  float4 a = *(const float4*)(in + i);
  float4 b = *(const float4*)(in + i + 4);
  u16x8 r;
  r[0] = f2b(a.x); r[1] = f2b(a.y); r[2] = f2b(a.z); r[3] = f2b(a.w);
  r[4] = f2b(b.x); r[5] = f2b(b.y); r[6] = f2b(b.z); r[7] = f2b(b.w);
  *(u16x8*)(out + i) = r;
}

__device__ __forceinline__ void wtrans_body(const float* __restrict__ in,
                                            unsigned short* __restrict__ out,
                                            int K, int N, int bx, int by,
                                            float (*tile)[33]) {
  const int k0 = by * 32, n0 = bx * 32;
  const int x = threadIdx.x & 31, y8 = threadIdx.x >> 5;
#pragma unroll
  for (int j = 0; j < 4; ++j) {
    const int y = y8 + j * 8;
    tile[y][x] = in[(size_t)(k0 + y) * N + n0 + x];
  }
  __syncthreads();
#pragma unroll
  for (int j = 0; j < 4; ++j) {
    const int y = y8 + j * 8;
    out[(size_t)(n0 + y) * K + k0 + x] = f2b(tile[x][y]);
  }
}

__global__ __launch_bounds__(256) void prep_all(const float* __restrict__ q_input,
                                                unsigned short* __restrict__ Qb16,
                                                const float* __restrict__ kv_input,
                                                unsigned short* __restrict__ KVb16,
                                                const float* __restrict__ Wq,
                                                unsigned short* __restrict__ Wqt,
                                                const float* __restrict__ Wk,
                                                const float* __restrict__ Wv,
                                                unsigned short* __restrict__ WkvT,
                                                const float* __restrict__ Wo,
                                                unsigned short* __restrict__ Wot) {
  __shared__ float tile[32][33];
  const int l = blockIdx.x;
  if (l < 4096) {
    f2bf_body(q_input, Qb16, l);
  } else if (l < 8192) {
    f2bf_body(kv_input, KVb16, l - 4096);
  } else if (l < 12288) {
    const int l2 = l - 8192;
    wtrans_body(Wq, Wqt, 2048, 2048, l2 & 63, l2 >> 6, tile);
  } else if (l < 13312) {
    const int l2 = l - 12288;
    wtrans_body(Wk, WkvT, 2048, 512, l2 & 15, l2 >> 4, tile);
  } else if (l < 14336) {
    const int l2 = l - 13312;
    wtrans_body(Wv, WkvT + (size_t)512 * 2048, 2048, 512, l2 & 15, l2 >> 4, tile);
  } else {
    const int l2 = l - 14336;
    wtrans_body(Wo, Wot, 2048, 2048, l2 & 63, l2 >> 6, tile);
  }
}

// ---------- GEMM compute core: acc = A(M,K)bf16 @ Bt(N,K)bf16^T tile (m0,n0) ----------
// 128x128 tile, BK=64, 2-phase double-buffered global_load_lds pipeline.
// Linear LDS [128][64]; conflict-free via XOR-granule swizzle on BOTH sides.
__device__ __forceinline__ void gemm_mm(const unsigned short* __restrict__ A,
                                        const unsigned short* __restrict__ Bt,
                                        int K, int m0, int n0,
                                        unsigned short* As, unsigned short* Bs,
                                        f32x4 (&acc)[4][4]) {
  const int tid = threadIdx.x;
  const int wave = tid >> 6, lane = tid & 63;
  const int wm = wave >> 1, wn = wave & 1;
  const int quad = lane >> 4, c = lane & 15;
  const int lr = lane >> 3;                 // 0..7: row within an 8-row stage group
  const int gsw = ((lane & 7) ^ lr) * 8;    // pre-swizzled source granule (shorts)

  const unsigned short* pa[4];
  const unsigned short* pb[4];
  unsigned short* da[4];
  unsigned short* db[4];
#pragma unroll
  for (int j = 0; j < 4; ++j) {
    const int rb = j * 32 + wave * 8;       // 8-row group base (multiple of 8)
    pa[j] = A + (size_t)(m0 + rb + lr) * K + gsw;
    pb[j] = Bt + (size_t)(n0 + rb + lr) * K + gsw;
    da[j] = As + rb * 64;
    db[j] = Bs + rb * 64;
  }

  const f32x4 zero = {0.f, 0.f, 0.f, 0.f};
#pragma unroll
  for (int sm = 0; sm < 4; ++sm)
#pragma unroll
    for (int sn = 0; sn < 4; ++sn) acc[sm][sn] = zero;

  const int nsteps = K >> 6;
  int cur = 0;

  // prologue: stage K-step 0 into buffer 0
#pragma unroll
  for (int j = 0; j < 4; ++j) { glds16(pa[j], da[j]); glds16(pb[j], db[j]); }
  __syncthreads();

  for (int t = 0; t < nsteps; ++t) {
    const int nxt = (cur ^ 1) * (128 * 64);
    if (t + 1 < nsteps) {  // issue next K-step's DMA; latency hides under MFMA
      const int kn = (t + 1) << 6;
#pragma unroll
      for (int j = 0; j < 4; ++j) {
        glds16(pa[j] + kn, da[j] + nxt);
        glds16(pb[j] + kn, db[j] + nxt);
      }
    }
    const unsigned short* Ab = As + cur * (128 * 64);
    const unsigned short* Bb = Bs + cur * (128 * 64);
#pragma unroll
    for (int kk = 0; kk < 2; ++kk) {
      const int g = ((kk * 4 + quad) ^ (c & 7)) * 8;  // swizzled read granule
      bf16x8 af[4];
#pragma unroll
      for (int sm = 0; sm < 4; ++sm)
        af[sm] = *(const bf16x8*)&Ab[(wm * 64 + sm * 16 + c) * 64 + g];
#pragma unroll
      for (int sn = 0; sn < 4; ++sn) {
        bf16x8 bfr = *(const bf16x8*)&Bb[(wn * 64 + sn * 16 + c) * 64 + g];
#pragma unroll
        for (int sm = 0; sm < 4; ++sm)
          acc[sm][sn] = __builtin_amdgcn_mfma_f32_16x16x32_bf16(af[sm], bfr, acc[sm][sn], 0, 0, 0);
      }
    }
    // drain own glds (vmcnt) + join: next buffer globally ready.
    __syncthreads();
    cur ^= 1;
  }
  // note: loop ends with __syncthreads -> LDS reusable by epilogues
}

// ---------- standalone GEMM (O-projection) ----------
__global__ __launch_bounds__(256) void gemm128(const unsigned short* __restrict__ A,
                                               const unsigned short* __restrict__ Bt,
                                               float* __restrict__ C,
                                               int M, int N, int K) {
  __shared__ __align__(16) unsigned char smem[65536];
  unsigned short* As = (unsigned short*)smem;
  unsigned short* Bs = (unsigned short*)(smem + 32768);
  const int gx = gridDim.x;
  const int nwg = gx * gridDim.y;
  int lin = blockIdx.y * gx + blockIdx.x;
  lin = (lin & 7) * (nwg >> 3) + (lin >> 3);  // T1 XCD swizzle (nwg%8==0)
  const int m0 = (lin / gx) * 128, n0 = (lin % gx) * 128;
  f32x4 acc[4][4];
  gemm_mm(A, Bt, K, m0, n0, As, Bs, acc);
  const int tid = threadIdx.x;
  const int wave = tid >> 6, lane = tid & 63;
  const int wm = wave >> 1, wn = wave & 1;
  const int quad = lane >> 4, c = lane & 15;
#pragma unroll
  for (int sm = 0; sm < 4; ++sm)
#pragma unroll
    for (int sn = 0; sn < 4; ++sn) {
      const int row = m0 + wm * 64 + sm * 16 + quad * 4;
      const int col = n0 + wn * 64 + sn * 16 + c;
#pragma unroll
      for (int r = 0; r < 4; ++r)
        C[(size_t)(row + r) * N + col] = acc[sm][sn][r];
    }
}

// ---------- epilogue: zc-rmsnorm + rope + bf16, straight from accumulators ----------
__device__ __forceinline__ void epi_normrope(f32x4 (&acc)[4][4], float* xb,
                                             unsigned short* __restrict__ dst,
                                             const float* __restrict__ scale,
                                             const float* __restrict__ cosp,
                                             const float* __restrict__ sinp,
                                             int t0, float outscale) {
  const int tid = threadIdx.x;
  const int wave = tid >> 6, lane = tid & 63;
  const int wm = wave >> 1, wn = wave & 1;
  const int quad = lane >> 4, c = lane & 15;
#pragma unroll
  for (int sm = 0; sm < 4; ++sm)
#pragma unroll
    for (int sn = 0; sn < 4; ++sn) {
      const int row = wm * 64 + sm * 16 + quad * 4;
      const int col = wn * 64 + sn * 16 + c;
#pragma unroll
      for (int r = 0; r < 4; ++r)
        xb[(row + r) * 128 + col] = acc[sm][sn][r];
    }
  __syncthreads();
#pragma unroll
  for (int sm = 0; sm < 4; ++sm) {
#pragma unroll
    for (int r = 0; r < 4; ++r) {
      const int row = wm * 64 + sm * 16 + quad * 4 + r;
      float par[4];
      float ps = 0.f;
#pragma unroll
      for (int sn = 0; sn < 4; ++sn) {
        const float own = acc[sm][sn][r];
        par[sn] = xb[row * 128 + ((wn ^ 1) * 64 + sn * 16 + c)];
        ps += own * own + par[sn] * par[sn];
      }
      ps += __shfl_xor(ps, 1, 64);
      ps += __shfl_xor(ps, 2, 64);
      ps += __shfl_xor(ps, 4, 64);
      ps += __shfl_xor(ps, 8, 64);
      const float inv = 1.0f / sqrtf(ps * (1.0f / NHD) + 1e-6f);
      const int t = t0 + row;
#pragma unroll
      for (int sn = 0; sn < 4; ++sn) {
        const int d = wn * 64 + sn * 16 + c;
        const int dd = sn * 16 + c;  // rope index (d & 63)
        const float n_own = (1.0f + scale[d]) * acc[sm][sn][r] * inv;
        const float n_par = (1.0f + scale[d ^ 64]) * par[sn] * inv;
        const float cc = cosp[t * NHALF + dd], ss = sinp[t * NHALF + dd];
        const float o = (wn == 0) ? (n_own * cc - n_par * ss)
                                  : (n_own * cc + n_par * ss);
        dst[(size_t)row * NHD + d] = f2b(o * outscale);
      }
    }
  }
}

// ---------- epilogue: V transpose via LDS -> Vtg[d][t] bf16, coalesced out ----------
__device__ __forceinline__ void epi_vtrans(f32x4 (&acc)[4][4],
                                           unsigned short* vb,  // [128][136]
                                           unsigned short* __restrict__ dst) {
  const int tid = threadIdx.x;
  const int wave = tid >> 6, lane = tid & 63;
  const int wm = wave >> 1, wn = wave & 1;
  const int quad = lane >> 4, c = lane & 15;
#pragma unroll
  for (int sm = 0; sm < 4; ++sm)
#pragma unroll
    for (int sn = 0; sn < 4; ++sn) {
      const int row = wm * 64 + sm * 16 + quad * 4;
      const int col = wn * 64 + sn * 16 + c;
      u16x4 pk;
      pk[0] = f2b(acc[sm][sn][0]); pk[1] = f2b(acc[sm][sn][1]);
      pk[2] = f2b(acc[sm][sn][2]); pk[3] = f2b(acc[sm][sn][3]);
      *(u16x4*)&vb[col * 136 + row] = pk;
    }
  __syncthreads();
#pragma unroll
  for (int i = 0; i < 32; ++i) {
    const int d = wave * 32 + i;
    const unsigned int v = *(const unsigned int*)&vb[d * 136 + lane * 2];
    *(unsigned int*)&dst[(size_t)d * NT + lane * 2] = v;
  }
}

// ---------- fused Q-proj + KV-proj + norm/rope/vtrans epilogues (768 blocks) ----------
__global__ __launch_bounds__(256) void gemm_qkv(const unsigned short* __restrict__ Aq,
                                                const unsigned short* __restrict__ Wqt,
                                                const unsigned short* __restrict__ Akv,
                                                const unsigned short* __restrict__ Wkv,
                                                unsigned short* __restrict__ Qh,
                                                unsigned short* __restrict__ Kh,
                                                unsigned short* __restrict__ Vtg,
                                                const float* __restrict__ q_scale,
                                                const float* __restrict__ k_scale,
                                                const float* __restrict__ cosp,
                                                const float* __restrict__ sinp) {
  __shared__ __align__(16) unsigned char smem[65536];
  unsigned short* As = (unsigned short*)smem;
  unsigned short* Bs = (unsigned short*)(smem + 32768);
  int lin = blockIdx.x;
  lin = (lin & 7) * 96 + (lin >> 3);  // XCD swizzle, nwg = 768
  f32x4 acc[4][4];
  if (lin < 512) {
    const int m0 = (lin >> 4) * 128, n0 = (lin & 15) * 128;
    gemm_mm(Aq, Wqt, 2048, m0, n0, As, Bs, acc);
    const int b = m0 >> 11, t0 = m0 & 2047, h = n0 >> 7;
    epi_normrope(acc, (float*)smem,
                 Qh + ((size_t)(b * NH + h) * NT + t0) * NHD,
                 q_scale, cosp, sinp, t0, 0.08838834764831845f);
  } else {
    const int l2 = lin - 512;
    const int m0 = (l2 >> 3) * 128, n0 = (l2 & 7) * 128;
    gemm_mm(Akv, Wkv, 2048, m0, n0, As, Bs, acc);
    const int b = m0 >> 11, t0 = m0 & 2047;
    if (n0 < 512) {
      const int g = n0 >> 7;
      epi_normrope(acc, (float*)smem,
                   Kh + ((size_t)(b * NKVH + g) * NT + t0) * NHD,
                   k_scale, cosp, sinp, t0, 1.0f);
    } else {
      const int g = (n0 - 512) >> 7;
      epi_vtrans(acc, (unsigned short*)smem,
                 Vtg + ((size_t)(b * NKVH + g) * NHD) * NT + t0);
    }
  }
}

// ---------- MFMA causal flash attention, 64-row Q-tiles ----------
// grid (B*H, 32). Block = 64 q-rows (4 waves x 16 rows), K-tiles of 64 keys.
// Fixed-max softmax (MFIX); T14 reg prefetch. Known-good r5 structure:
// single-buffered K/V LDS, two __syncthreads per tile, NO setprio (r6: -13%),
// NO runtime-indexed LDS dbuf (r7: compiler devectorized LDS ops, -3.6x).
// LDS strides 132/68 shorts; LDS 43008 B -> 3 blocks/CU.
__global__ __launch_bounds__(256, 3) void attn64(const unsigned short* __restrict__ Qh,
                                                 const unsigned short* __restrict__ Kh,
                                                 const unsigned short* __restrict__ Vtg,
                                                 unsigned short* __restrict__ O) {
  __shared__ unsigned short Kt[64 * 132];  // [key][d]
  __shared__ unsigned short Vt[128 * 68];  // [d][key]
  __shared__ unsigned short Pt[64 * 68];   // [qrow][key], wave-private 16-row slabs
  const int bh = blockIdx.x;
  const int b = bh / NH, h = bh % NH, g = h / NREP;
  const int y = blockIdx.y;
  const int a = y & 7, bb = y >> 3;
  // CU-balanced qt map: each a-group gets {a, a+8, 31-a, 23-a} (sum = 62, constant)
  const int qt = (bb == 0) ? a : (bb == 1) ? a + 8 : (bb == 2) ? 31 - a : 23 - a;
  const int tid = threadIdx.x;
  const int w = tid >> 6, lane = tid & 63;
  const int quad = lane >> 4, c = lane & 15;

  // Q A-fragments: rows qt*64 + w*16 + c, k = ch*32 + quad*8 + j
  bf16x8 qf[4];
  {
    const unsigned short* qp =
        Qh + ((size_t)(b * NH + h) * NT + qt * 64 + w * 16 + c) * NHD + quad * 8;
#pragma unroll
    for (int ch = 0; ch < 4; ++ch) qf[ch] = *(const bf16x8*)(qp + ch * 32);
  }

  f32x4 acc_o[8] = {};              // [n2]: row quad*4+r, dim n2*16+c
  float lsum[4] = {0.f, 0.f, 0.f, 0.f};
  const size_t kbase = (size_t)(b * NKVH + g) * NT * NHD;
  const size_t vbase = (size_t)(b * NKVH + g) * NHD * NT;
  const int nkt = qt + 1;

  // prologue: K/V tile 0 -> regs
  u16x8 kreg[4], vreg[4];
#pragma unroll
  for (int j = 0; j < 4; ++j) {
    const int f = j * 256 + tid;
    kreg[j] = *(const u16x8*)&Kh[kbase + (size_t)(f >> 4) * NHD + (f & 15) * 8];
    vreg[j] = *(const u16x8*)&Vtg[vbase + (size_t)(f >> 3) * NT + (f & 7) * 8];
  }

  for (int kt = 0; kt < nkt; ++kt) {
    // write staged tile to LDS
#pragma unroll
    for (int j = 0; j < 4; ++j) {
      const int f = j * 256 + tid;
      *(u16x8*)&Kt[(f >> 4) * 132 + (f & 15) * 8] = kreg[j];
      *(u16x8*)&Vt[(f >> 3) * 68 + (f & 7) * 8] = vreg[j];
    }
    __syncthreads();

    // prefetch next tile into regs (vmcnt drains at end-of-iter barrier,
    // hidden under QK+softmax+PV)
    if (kt + 1 < nkt) {
      const int k0 = (kt + 1) * 64;
#pragma unroll
      for (int j = 0; j < 4; ++j) {
        const int f = j * 256 + tid;
        kreg[j] = *(const u16x8*)&Kh[kbase + (size_t)(k0 + (f >> 4)) * NHD + (f & 15) * 8];
        vreg[j] = *(const u16x8*)&Vtg[vbase + (size_t)(f >> 3) * NT + k0 + (f & 7) * 8];
      }
    }

    // ---- S = Q K^T (16 x 64) ----
    f32x4 s[4] = {};
#pragma unroll
    for (int n = 0; n < 4; ++n)
#pragma unroll
      for (int ch = 0; ch < 4; ++ch) {
        bf16x8 kf = *(const bf16x8*)&Kt[(n * 16 + c) * 132 + ch * 32 + quad * 8];
        s[n] = __builtin_amdgcn_mfma_f32_16x16x32_bf16(qf[ch], kf, s[n], 0, 0, 0);
      }

    // ---- fixed-max softmax; P -> LDS (bf16) ----
    const bool dmask = (kt == qt);  // only the diagonal tile masks
#pragma unroll
    for (int r = 0; r < 4; ++r) {
      float v0 = s[0][r], v1 = s[1][r], v2 = s[2][r], v3 = s[3][r];
      const int lrow = w * 16 + quad * 4 + r;  // row within block; key offset n*16+c
      if (dmask) {
        if (c > lrow) v0 = -1e30f;
        if (16 + c > lrow) v1 = -1e30f;
        if (32 + c > lrow) v2 = -1e30f;
        if (48 + c > lrow) v3 = -1e30f;
      }
      const float p0 = __expf(v0 - MFIX), p1 = __expf(v1 - MFIX);
      const float p2 = __expf(v2 - MFIX), p3 = __expf(v3 - MFIX);
      lsum[r] += (p0 + p1) + (p2 + p3);
      Pt[lrow * 68 + c] = f2b(p0);
      Pt[lrow * 68 + 16 + c] = f2b(p1);
      Pt[lrow * 68 + 32 + c] = f2b(p2);
      Pt[lrow * 68 + 48 + c] = f2b(p3);
    }

    // ---- O += P V ----
#pragma unroll
    for (int kc2 = 0; kc2 < 2; ++kc2) {
      bf16x8 pf = *(const bf16x8*)&Pt[(w * 16 + c) * 68 + kc2 * 32 + quad * 8];
#pragma unroll
      for (int n2 = 0; n2 < 8; ++n2) {
        bf16x8 vf = *(const bf16x8*)&Vt[(n2 * 16 + c) * 68 + kc2 * 32 + quad * 8];
        acc_o[n2] = __builtin_amdgcn_mfma_f32_16x16x32_bf16(pf, vf, acc_o[n2], 0, 0, 0);
      }
    }
    __syncthreads();
  }

  // one cross-lane l reduction (within 16-lane c-group)
#pragma unroll
  for (int r = 0; r < 4; ++r) {
    float l = lsum[r];
    l += __shfl_xor(l, 1, 64);
    l += __shfl_xor(l, 2, 64);
    l += __shfl_xor(l, 4, 64);
    l += __shfl_xor(l, 8, 64);
    lsum[r] = l;
  }

#pragma unroll
  for (int r = 0; r < 4; ++r) {
    const float invl = 1.0f / lsum[r];
    const int qrow = qt * 64 + w * 16 + quad * 4 + r;
    unsigned short* op = O + ((size_t)(b * NT + qrow) * NH + h) * NHD + c;
#pragma unroll
    for (int n2 = 0; n2 < 8; ++n2) op[n2 * 16] = f2b(acc_o[n2][r] * invl);
  }
}

extern "C" void kernel_launch(void* const* d_in, const int* in_sizes, int n_in,
                              void* d_out, int out_size, void* d_ws, size_t ws_size,
                              hipStream_t stream) {
  (void)in_sizes; (void)n_in; (void)out_size; (void)ws_size;
  const float* q_input  = (const float*)d_in[0];
  const float* kv_input = (const float*)d_in[1];
  // d_in[2] = mask (static causal tril) — applied analytically
  const float* cosp = (const float*)d_in[3];
  const float* sinp = (const float*)d_in[4];
  const float* Wq = (const float*)d_in[5];
  const float* Wk = (const float*)d_in[6];
  const float* Wv = (const float*)d_in[7];
  const float* q_scale = (const float*)d_in[8];
  const float* k_scale = (const float*)d_in[9];
  const float* Wo = (const float*)d_in[10];
  float* out = (float*)d_out;

  // workspace carve (~80 MB)
  char* p = (char*)d_ws;
  unsigned short* Qb16  = (unsigned short*)p; p += (size_t)NB * NT * ND * 2;  // 16.8 MB
  unsigned short* KVb16 = (unsigned short*)p; p += (size_t)NB * NT * ND * 2;  // 16.8 MB
  unsigned short* Qh  = (unsigned short*)p; p += (size_t)NB * NH * NT * NHD * 2;    // 16.8 MB
  unsigned short* Kh  = (unsigned short*)p; p += (size_t)NB * NKVH * NT * NHD * 2;  // 4.2 MB
  unsigned short* Vtg = (unsigned short*)p; p += (size_t)NB * NKVH * NT * NHD * 2;  // 4.2 MB
  unsigned short* Wqt  = (unsigned short*)p; p += (size_t)ND * ND * 2;         // 8.4 MB
  unsigned short* WkvT = (unsigned short*)p; p += (size_t)1024 * ND * 2;       // 4.2 MB
  unsigned short* Wot  = (unsigned short*)p; p += (size_t)ND * ND * 2;         // 8.4 MB
  // alias: Qb16 dead after gemm_qkv -> reuse as attention output Ob
  unsigned short* Ob = Qb16;

  const dim3 blk(256);
  const int M = NB * NT;  // 4096

  // 1) all prep (activation cvt + weight transposes) in one dispatch
  prep_all<<<dim3(18432), blk, 0, stream>>>(q_input, Qb16, kv_input, KVb16,
                                            Wq, Wqt, Wk, Wv, WkvT, Wo, Wot);

  // 2) Q-proj + KV-proj + norm/rope/vtrans epilogues, one dispatch (768 blocks)
  gemm_qkv<<<dim3(768), blk, 0, stream>>>(Qb16, Wqt, KVb16, WkvT,
                                          Qh, Kh, Vtg, q_scale, k_scale, cosp, sinp);

  // 3) MFMA causal GQA flash attention -> Ob (B,T,H,HD)
  attn64<<<dim3(NB * NH, 32), blk, 0, stream>>>(Qh, Kh, Vtg, Ob);

  // 4) output projection -> d_out (f32)
  gemm128<<<dim3(ND / 128, M / 128), blk, 0, stream>>>(Ob, Wot, out, M, ND, ND);
}